// Round 3
// baseline (251.549 us; speedup 1.0000x reference)
//
#include <hip/hip_runtime.h>

typedef unsigned short u16;
typedef unsigned int   u32;
typedef __attribute__((ext_vector_type(4))) float f32x4;
typedef __attribute__((ext_vector_type(8))) short s16x8;
typedef __attribute__((ext_vector_type(4))) short s16x4;
typedef __attribute__((ext_vector_type(4))) unsigned short u16x4;

#define HW    36864
#define NCH   256
#define NB    4
#define NPIX  147456
#define POS   85
#define BN_EPS 1e-5f
#define NBKT  16

// ---- workspace float offsets ----
#define WS_PALL    0                           // 4*256*85
#define WS_YD      87040                       // 4*256*85
#define WS_PSUM    174080                      // 1024
#define WS_PSQ     175104                      // 1024
#define WS_CONTRIB 176128                      // 4*256*64
#define WS_FSUMB   241664                      // 16*256
#define WS_FSQB    245760                      // 16*256
#define WS_RM      249856                      // 4*256*192*8 = 1572864
#define WS_WPK     1822720                     // u16[65536] = 32768 floats
#define WS_XT      1855488                     // u16 xT: 4*36864*256 = 18874368 floats
#define WS_YBF     20729856                    // u16 y: 18874368 floats
#define WS_TOT1    39604224                    // tier1 floats
#define WS_TOT2    20729856                    // tier2 floats (no YBF)

__device__ __forceinline__ u16 f2bf(float f) {
  u32 u = __builtin_bit_cast(u32, f);
  u += 0x7fffu + ((u >> 16) & 1u);
  return (u16)(u >> 16);
}
__device__ __forceinline__ float bf2f(u16 h) {
  u32 u = ((u32)h) << 16;
  return __builtin_bit_cast(float, u);
}
__device__ __forceinline__ void gl_lds16(const void* g, void* l) {
  __builtin_amdgcn_global_load_lds(
      (const __attribute__((address_space(1))) u32*)g,
      (__attribute__((address_space(3))) u32*)l, 16, 0, 0);
}

#define LP 204   // LDS pitch (u16) for k_prep transpose tile

// K1: blocks 0..767: (b,r): read x row-block, emit rowmax + xT bf16 (swizzled).
//     blocks 768..799: pack wf[:, :256] -> bf16 frags; block 768 zeros accumulators.
__global__ __launch_bounds__(256) void k_prep(const float* __restrict__ x,
                                              const float* __restrict__ wf,
                                              float* __restrict__ wsb) {
  int blk = blockIdx.x;
  int t = threadIdx.x;
  if (blk >= 768) {
    int fid = (blk - 768)*256 + t;           // 0..8191: [ks][g][m]
    int m = fid & 255, g = (fid >> 8) & 3, ks = fid >> 10;
    const float* src = wf + (size_t)m*1280 + ks*32 + g*8;
    f32x4 a = *(const f32x4*)src;
    f32x4 c = *(const f32x4*)(src + 4);
    u32* dst = (u32*)((u16*)(wsb + WS_WPK) + (size_t)fid*8);
    dst[0] = (u32)f2bf(a.x) | ((u32)f2bf(a.y) << 16);
    dst[1] = (u32)f2bf(a.z) | ((u32)f2bf(a.w) << 16);
    dst[2] = (u32)f2bf(c.x) | ((u32)f2bf(c.y) << 16);
    dst[3] = (u32)f2bf(c.z) | ((u32)f2bf(c.w) << 16);
    if (blk == 768) {
      for (int i = t; i < 2048;  i += 256) wsb[WS_PSUM + i] = 0.f;
      for (int i = t; i < 65536; i += 256) wsb[WS_CONTRIB + i] = 0.f;
      for (int i = t; i < 8192;  i += 256) wsb[WS_FSUMB + i] = 0.f;
    }
    return;
  }
  __shared__ u16 ldsT[32 * LP];                // [c_local][px], 13 KB
  int b = blk / 192, r = blk % 192;
  int c_l = t >> 3, grp = t & 7;               // 32 channels x 8 col-groups
  int px_w = t >> 2, oct_w = t & 3;            // write-phase map
  u16* xTu = (u16*)(wsb + WS_XT);
  float* rm = wsb + WS_RM;
  int p_row = r * 192;

  for (int cc = 0; cc < 8; cc++) {
    int c = cc*32 + c_l;
    const float* src = x + (size_t)(b*NCH + c)*HW + p_row + grp*24;
    float mm = -3.4e38f;
    #pragma unroll
    for (int q = 0; q < 6; q++) {
      f32x4 v = *(const f32x4*)(src + q*4);
      mm = fmaxf(mm, fmaxf(fmaxf(v.x, v.y), fmaxf(v.z, v.w)));
      s16x4 pk;
      pk[0] = (short)f2bf(v.x); pk[1] = (short)f2bf(v.y);
      pk[2] = (short)f2bf(v.z); pk[3] = (short)f2bf(v.w);
      *(s16x4*)&ldsT[c_l*LP + grp*24 + q*4] = pk;
    }
    rm[((size_t)(b*NCH + c)*192 + r)*8 + grp] = mm;
    __syncthreads();
    // transposed write: 3 pixels-per-thread x 8 channels (one octet), swizzled slot
    #pragma unroll
    for (int i = 0; i < 3; i++) {
      int px = i*64 + px_w;
      s16x8 v;
      #pragma unroll
      for (int e = 0; e < 8; e++)
        v[e] = (short)ldsT[(oct_w*8 + e)*LP + px];
      int p_glob = p_row + px;
      int slot = oct_w ^ ((px >> 1) & 3);
      *(s16x8*)(xTu + ((size_t)b*HW + p_glob)*256 + cc*32 + slot*8) = v;
    }
    __syncthreads();
  }
}

// K2: (b,c) -> pyramid of block maxes pall[bc][85] from rowmax
__global__ __launch_bounds__(64) void k_pmax(float* __restrict__ wsb) {
  __shared__ float sm3[64], sm2[16], sm1[4], arr85[85];
  int bc = blockIdx.x;
  int t = threadIdx.x;
  const float* rm = wsb + WS_RM + (size_t)bc*1536;   // [192 r][8 bc]
  float v[24];
  #pragma unroll
  for (int q = 0; q < 6; q++)
    *(f32x4*)&v[q*4] = *(const f32x4*)(rm + t*24 + q*4);
  float m3p[8];
  #pragma unroll
  for (int j = 0; j < 8; j++)
    m3p[j] = fmaxf(v[j], fmaxf(v[8+j], v[16+j]));
  #pragma unroll
  for (int j = 0; j < 8; j++) {
    float m = m3p[j];
    m = fmaxf(m, __shfl_xor(m, 1));
    m = fmaxf(m, __shfl_xor(m, 2));
    m = fmaxf(m, __shfl_xor(m, 4));
    m3p[j] = m;
  }
  if ((t & 7) == 0) {
    int br = t >> 3;
    #pragma unroll
    for (int j = 0; j < 8; j++) sm3[br*8 + j] = m3p[j];
  }
  __syncthreads();
  if (t < 16) {
    int i = t >> 2, j = t & 3;
    sm2[t] = fmaxf(fmaxf(sm3[(2*i)*8 + 2*j], sm3[(2*i)*8 + 2*j + 1]),
                   fmaxf(sm3[(2*i+1)*8 + 2*j], sm3[(2*i+1)*8 + 2*j + 1]));
  }
  __syncthreads();
  if (t < 4) {
    int i = t >> 1, j = t & 1;
    sm1[t] = fmaxf(fmaxf(sm2[(2*i)*4 + 2*j], sm2[(2*i)*4 + 2*j + 1]),
                   fmaxf(sm2[(2*i+1)*4 + 2*j], sm2[(2*i+1)*4 + 2*j + 1]));
  }
  __syncthreads();
  if (t < 64) arr85[t] = sm3[t];
  if (t < 16) arr85[64 + t] = sm2[t];
  if (t < 4)  arr85[80 + t] = sm1[t];
  if (t == 0) arr85[84] = fmaxf(fmaxf(sm1[0], sm1[1]), fmaxf(sm1[2], sm1[3]));
  __syncthreads();
  float* pb = wsb + WS_PALL + (size_t)bc*POS;
  if (t < 85) pb[t] = arr85[t];
  if (t >= 21 && t < 42) pb[t + 43] = arr85[t + 43]; // cover 64..84 via second write? (no-op guard)
}

// K3: pyramid convs on distinct block values + BN stat accumulation
__global__ __launch_bounds__(256) void k_pyr(const float* __restrict__ wconv, float* __restrict__ wsb) {
  __shared__ __align__(16) float pv[256];
  int bi = blockIdx.x;                       // b*85 + pos
  int b = bi / 85, pos = bi % 85;
  int d = (pos < 64) ? 3 : (pos < 80) ? 2 : (pos < 84) ? 1 : 0;
  int t = threadIdx.x;
  pv[t] = wsb[WS_PALL + (size_t)(b*NCH + t)*POS + pos];
  __syncthreads();
  const float* wrow = wconv + ((size_t)d*NCH + t)*NCH;
  float acc = 0.f;
  #pragma unroll 4
  for (int c4 = 0; c4 < 64; c4++) {
    f32x4 wv = *(const f32x4*)(wrow + c4*4);
    f32x4 xv = *(const f32x4*)(&pv[c4*4]);
    acc += wv.x*xv.x + wv.y*xv.y + wv.z*xv.z + wv.w*xv.w;
  }
  wsb[WS_YD + (size_t)(b*NCH + t)*POS + pos] = acc;
  atomicAdd(&wsb[WS_PSUM + d*NCH + t], acc);
  atomicAdd(&wsb[WS_PSQ  + d*NCH + t], acc*acc);
}

// K4: contrib[b][o][cell] += sum over depth-d channels (grid = d*64 + cell)
__global__ __launch_bounds__(256) void k_contrib(const float* __restrict__ wf,
                                                 const float* __restrict__ gs,
                                                 const float* __restrict__ bs,
                                                 float* __restrict__ wsb) {
  __shared__ __align__(16) float pn[4][256];
  int bi = blockIdx.x;
  int d = bi >> 6, cell = bi & 63;
  int by = cell >> 3, bx = cell & 7;
  int t = threadIdx.x;
  int pos = (d == 3) ? cell
          : (d == 2) ? 64 + (by >> 1)*4 + (bx >> 1)
          : (d == 1) ? 80 + (by >> 2)*2 + (bx >> 2)
          : 84;
  // inline pstats for (d, c=t)
  float cnt = (float)(4 << (2*d));
  float mu  = wsb[WS_PSUM + d*NCH + t] / cnt;
  float var = wsb[WS_PSQ  + d*NCH + t] / cnt - mu*mu;
  float sc  = gs[d*NCH + t] * rsqrtf(var + BN_EPS);
  float bi_ = bs[d*NCH + t] - mu * sc;
  #pragma unroll
  for (int b = 0; b < 4; b++)
    pn[b][t] = wsb[WS_YD + (size_t)(b*NCH + t)*POS + pos] * sc + bi_;
  __syncthreads();
  const float* wrow = wf + (size_t)t*1280 + 256 + d*256;
  float a0 = 0.f, a1 = 0.f, a2 = 0.f, a3 = 0.f;
  #pragma unroll 4
  for (int j = 0; j < 64; j++) {
    f32x4 wv = *(const f32x4*)(wrow + j*4);
    f32x4 p0 = *(const f32x4*)(&pn[0][j*4]);
    f32x4 p1 = *(const f32x4*)(&pn[1][j*4]);
    f32x4 p2 = *(const f32x4*)(&pn[2][j*4]);
    f32x4 p3 = *(const f32x4*)(&pn[3][j*4]);
    a0 += wv.x*p0.x + wv.y*p0.y + wv.z*p0.z + wv.w*p0.w;
    a1 += wv.x*p1.x + wv.y*p1.y + wv.z*p1.z + wv.w*p1.w;
    a2 += wv.x*p2.x + wv.y*p2.y + wv.z*p2.z + wv.w*p2.w;
    a3 += wv.x*p3.x + wv.y*p3.y + wv.z*p3.z + wv.w*p3.w;
  }
  atomicAdd(&wsb[WS_CONTRIB + (size_t)(0*NCH + t)*64 + cell], a0);
  atomicAdd(&wsb[WS_CONTRIB + (size_t)(1*NCH + t)*64 + cell], a1);
  atomicAdd(&wsb[WS_CONTRIB + (size_t)(2*NCH + t)*64 + cell], a2);
  atomicAdd(&wsb[WS_CONTRIB + (size_t)(3*NCH + t)*64 + cell], a3);
}

// K5: main GEMM  y = wfL . x  via bf16 MFMA, global_load_lds staging from xT
template<bool YBF>
__global__ __launch_bounds__(256, 3) void k_main(float* __restrict__ wsb, float* __restrict__ y) {
  __shared__ __align__(16) u16 xlds[2][128*32];   // [buf][px][32k] = 8KB each
  int wg = blockIdx.x;
  int b = wg / 288, tile = wg % 288;
  int n0 = tile * 128;
  int t = threadIdx.x;
  int wave = t >> 6, l = t & 63;
  int g = l >> 4, ln = l & 15;
  int spix = t >> 2, soct = t & 3;
  const u16* xT = (const u16*)(wsb + WS_XT) + (size_t)b*HW*256;
  const u16* wpk = (const u16*)(wsb + WS_WPK);

  f32x4 acc[4][8];
  #pragma unroll
  for (int i = 0; i < 4; i++)
    #pragma unroll
    for (int j = 0; j < 8; j++)
      acc[i][j] = {0.f, 0.f, 0.f, 0.f};

  // prologue: stage ks=0 into buf 0
  {
    const u16* s0 = xT + (size_t)(n0 + spix)*256 + soct*8;
    gl_lds16(s0, &xlds[0][spix*32 + soct*8]);
    gl_lds16(s0 + 64*256, &xlds[0][(64 + spix)*32 + soct*8]);
  }

  s16x8 af[4];
  #pragma unroll
  for (int ks = 0; ks < 8; ks++) {
    int abase = (ks*4 + g)*256 + wave*64 + ln;
    #pragma unroll
    for (int tm = 0; tm < 4; tm++)
      af[tm] = *(const s16x8*)(wpk + (size_t)(abase + tm*16)*8);
    __syncthreads();                             // drains this wave's loads, LDS visible
    if (ks < 7) {
      const u16* s0 = xT + (size_t)(n0 + spix)*256 + (ks + 1)*32 + soct*8;
      u16* d0 = &xlds[(ks + 1) & 1][spix*32 + soct*8];
      gl_lds16(s0, d0);
      gl_lds16(s0 + 64*256, d0 + 64*32);
    }
    const u16* xb = xlds[ks & 1];
    #pragma unroll
    for (int tn = 0; tn < 8; tn++) {
      int n = tn*16 + ln;
      s16x8 bfr = *(const s16x8*)(xb + n*32 + ((g ^ ((n >> 1) & 3))*8));
      #pragma unroll
      for (int tm = 0; tm < 4; tm++)
        acc[tm][tn] = __builtin_amdgcn_mfma_f32_16x16x32_bf16(af[tm], bfr, acc[tm][tn], 0, 0, 0);
    }
  }

  // epilogue: add contrib, store y, accumulate channel stats
  const float* cb = wsb + WS_CONTRIB + (size_t)b*NCH*64;
  int bkt = wg & (NBKT - 1);
  float* fsum = wsb + WS_FSUMB + bkt*256;
  float* fsq  = wsb + WS_FSQB  + bkt*256;
  u16*   ybb  = (u16*)(wsb + WS_YBF) + (size_t)b*NCH*HW + n0;
  float* yf   = y + (size_t)b*NCH*HW + n0;
  #pragma unroll
  for (int tm = 0; tm < 4; tm++) {
    int ob = wave*64 + tm*16 + g*4;
    #pragma unroll
    for (int r_ = 0; r_ < 4; r_++) {
      int o = ob + r_;
      const float* cbo = cb + (size_t)o*64;
      float s1 = 0.f, s2 = 0.f;
      #pragma unroll
      for (int tn = 0; tn < 8; tn++) {
        int n = tn*16 + ln;
        u32 p = (u32)(n0 + n);
        u32 row = p / 192u;
        u32 col = p - row*192u;
        float yv = acc[tm][tn][r_] + cbo[(row/24u)*8u + col/24u];
        if (YBF) {
          u16 h = f2bf(yv);
          float yr = bf2f(h);
          ybb[(size_t)o*HW + n] = h;
          s1 += yr; s2 += yr*yr;
        } else {
          yf[(size_t)o*HW + n] = yv;
          s1 += yv; s2 += yv*yv;
        }
      }
      s1 += __shfl_xor(s1, 1);  s2 += __shfl_xor(s2, 1);
      s1 += __shfl_xor(s1, 2);  s2 += __shfl_xor(s2, 2);
      s1 += __shfl_xor(s1, 4);  s2 += __shfl_xor(s2, 4);
      s1 += __shfl_xor(s1, 8);  s2 += __shfl_xor(s2, 8);
      if (ln == 0) { atomicAdd(&fsum[o], s1); atomicAdd(&fsq[o], s2); }
    }
  }
}

// K6: normalize with inline final BN stats
template<bool YBF>
__global__ __launch_bounds__(256) void k_norm(float* __restrict__ out,
                                              const float* __restrict__ gf,
                                              const float* __restrict__ bfv,
                                              const float* __restrict__ wsb) {
  int bid = blockIdx.x;                      // plane*4 + quarter
  int plane = bid >> 2, q = bid & 3;
  int c = plane & 255;
  float s1 = 0.f, s2 = 0.f;
  #pragma unroll
  for (int i = 0; i < NBKT; i++) {
    s1 += wsb[WS_FSUMB + i*256 + c];
    s2 += wsb[WS_FSQB  + i*256 + c];
  }
  float inv = 1.f / (float)NPIX;
  float mu  = s1 * inv;
  float var = s2 * inv - mu*mu;
  float sc  = gf[c] * rsqrtf(var + BN_EPS);
  float bi  = bfv[c] - mu * sc;
  size_t base4 = ((size_t)plane*HW + q*(HW/4)) >> 2;
  int t = threadIdx.x;
  if (YBF) {
    const u16* yb = (const u16*)(wsb + WS_YBF);
    #pragma unroll
    for (int it = 0; it < 9; it++) {
      size_t i4 = base4 + it*256 + t;
      u16x4 v = *(const u16x4*)(yb + i4*4);
      f32x4 o;
      o.x = bf2f(v.x)*sc + bi;
      o.y = bf2f(v.y)*sc + bi;
      o.z = bf2f(v.z)*sc + bi;
      o.w = bf2f(v.w)*sc + bi;
      ((f32x4*)out)[i4] = o;
    }
  } else {
    #pragma unroll
    for (int it = 0; it < 9; it++) {
      size_t i4 = base4 + it*256 + t;
      f32x4 v = ((f32x4*)out)[i4];
      v.x = v.x*sc + bi; v.y = v.y*sc + bi; v.z = v.z*sc + bi; v.w = v.w*sc + bi;
      ((f32x4*)out)[i4] = v;
    }
  }
}

extern "C" void kernel_launch(void* const* d_in, const int* in_sizes, int n_in,
                              void* d_out, int out_size, void* d_ws, size_t ws_size,
                              hipStream_t stream) {
  const float* x  = (const float*)d_in[0];
  const float* w  = (const float*)d_in[1];
  const float* gs = (const float*)d_in[2];
  const float* bs = (const float*)d_in[3];
  const float* wf = (const float*)d_in[4];
  const float* gf = (const float*)d_in[5];
  const float* bf = (const float*)d_in[6];
  float* y   = (float*)d_out;
  float* wsb = (float*)d_ws;

  bool ybf = ws_size >= (size_t)WS_TOT1 * sizeof(float);

  k_prep   <<<800, 256, 0, stream>>>(x, wf, wsb);
  k_pmax   <<<NB*NCH, 64, 0, stream>>>(wsb);
  k_pyr    <<<NB*POS, 256, 0, stream>>>(w, wsb);
  k_contrib<<<256, 256, 0, stream>>>(wf, gs, bs, wsb);
  if (ybf) k_main<true> <<<NB*288, 256, 0, stream>>>(wsb, y);
  else     k_main<false><<<NB*288, 256, 0, stream>>>(wsb, y);
  if (ybf) k_norm<true> <<<4096, 256, 0, stream>>>(y, gf, bf, wsb);
  else     k_norm<false><<<4096, 256, 0, stream>>>(y, gf, bf, wsb);
}